// Round 23
// baseline (257.433 us; speedup 1.0000x reference)
//
#include <hip/hip_runtime.h>
#include <hip/hip_bf16.h>

#define NQ   16384
#define DIM  256

using bf16 = __hip_bfloat16;
using bf16x8 = __attribute__((ext_vector_type(8))) short;
using f32x4  = __attribute__((ext_vector_type(4))) float;

__device__ __forceinline__ float b2f(bf16 x) { return __bfloat162float(x); }
__device__ __forceinline__ bf16  f2b(float x) { return __float2bfloat16(x); }
__device__ __forceinline__ unsigned short f2bb(float x) {
    bf16 h = __float2bfloat16(x);
    return *(unsigned short*)&h;
}
__device__ __forceinline__ float us2f(unsigned short u) {
    unsigned int x = ((unsigned int)u) << 16;
    return __builtin_bit_cast(float, x);
}
__device__ __forceinline__ bf16x8 pack8(const float* f) {
    bf16x8 r;
#pragma unroll
    for (int j = 0; j < 8; ++j) r[j] = (short)f2bb(f[j]);
    return r;
}

// Bijective XCD-aware block remap (m204)
__device__ __forceinline__ void xcd_map(int& sx, int& sy)
{
    const int gx  = gridDim.x;
    const int nwg = gridDim.x * gridDim.y;
    const int bid = blockIdx.y * gx + blockIdx.x;
    const int q = nwg >> 3, r = nwg & 7;
    const int xcd = bid & 7, sl = bid >> 3;
    const int s = (xcd < r ? xcd * (q + 1) : r * (q + 1) + (xcd - r) * q) + sl;
    sx = s % gx;
    sy = s / gx;
}

// ---------------------------------------------------------------------------
// Barrier-free B-panel GEMM core, M-split, SOFTWARE-PIPELINED.
// C[M,N] = A[M,K] @ B[N,K]^T + bias (+res) (+QP: C2 = C + pos(row,col)).
// ---------------------------------------------------------------------------
template<int MW, int NF, int KS>
__device__ __forceinline__ void gcore(
    bf16* __restrict__ Bs,
    const bf16* __restrict__ A, const bf16* __restrict__ Bgl,
    const float* __restrict__ bias, const bf16* __restrict__ res,
    const float* __restrict__ ce, const float* __restrict__ re,
    bf16* __restrict__ C, bf16* __restrict__ C2,
    int N, int n0, int m0)
{
    constexpr int K   = KS * 32;
    constexpr int LDB = K + 8;

    const int t    = threadIdx.x;
    const int lane = t & 63;
    const int wid  = t >> 6;
    const int lr   = lane & 15;
    const int lg   = lane >> 4;

    const bf16* Ab = A + (size_t)(m0 + wid * MW * 16 + lr) * K + lg * 8;

    bf16x8 af0[MW], af1[MW], af2[MW];
#pragma unroll
    for (int mi = 0; mi < MW; ++mi)
        af0[mi] = *(const bf16x8*)&Ab[(size_t)(mi * 16) * K + 0];
    if (KS > 1) {
#pragma unroll
        for (int mi = 0; mi < MW; ++mi)
            af1[mi] = *(const bf16x8*)&Ab[(size_t)(mi * 16) * K + 32];
    }

#pragma unroll
    for (int c = 0; c < NF * KS / 4; ++c) {
        const int id  = c * 256 + t;
        const int row = id / (KS * 4);
        const int kc  = id % (KS * 4);
        *(int4*)&Bs[row * LDB + kc * 8] = *(const int4*)&Bgl[(size_t)row * K + kc * 8];
    }
    __syncthreads();

    f32x4 acc[MW][NF];
#pragma unroll
    for (int i = 0; i < MW; ++i)
#pragma unroll
        for (int j = 0; j < NF; ++j) {
            f32x4 z = {0.f, 0.f, 0.f, 0.f};
            acc[i][j] = z;
        }

    bf16x8 bcur[NF], bnxt[NF];
#pragma unroll
    for (int jj = 0; jj < NF; ++jj)
        bcur[jj] = *(const bf16x8*)&Bs[(jj * 16 + lr) * LDB + lg * 8];

#pragma unroll
    for (int s = 0; s < KS; ++s) {
        if (s + 2 < KS) {
#pragma unroll
            for (int mi = 0; mi < MW; ++mi)
                af2[mi] = *(const bf16x8*)&Ab[(size_t)(mi * 16) * K + (s + 2) * 32];
        }
        if (s + 1 < KS) {
#pragma unroll
            for (int jj = 0; jj < NF; ++jj)
                bnxt[jj] = *(const bf16x8*)&Bs[(jj * 16 + lr) * LDB + (s + 1) * 32 + lg * 8];
        }
#pragma unroll
        for (int mi = 0; mi < MW; ++mi)
#pragma unroll
            for (int jj = 0; jj < NF; ++jj)
                acc[mi][jj] = __builtin_amdgcn_mfma_f32_16x16x32_bf16(
                    af0[mi], bcur[jj], acc[mi][jj], 0, 0, 0);
#pragma unroll
        for (int mi = 0; mi < MW; ++mi) { af0[mi] = af1[mi]; af1[mi] = af2[mi]; }
#pragma unroll
        for (int jj = 0; jj < NF; ++jj) bcur[jj] = bnxt[jj];
    }

    const bool dores = res != nullptr;
    const bool doqp  = C2 != nullptr;
    // C/D layout: col = lane&15, row = (lane>>4)*4 + reg
#pragma unroll
    for (int mi = 0; mi < MW; ++mi) {
#pragma unroll
        for (int jj = 0; jj < NF; ++jj) {
            const int row0 = m0 + wid * MW * 16 + mi * 16 + lg * 4;
            const int col  = n0 + jj * 16 + lr;
            const float bvl = bias[col];
#pragma unroll
            for (int r = 0; r < 4; ++r) {
                const size_t off = (size_t)(row0 + r) * N + col;
                float v = acc[mi][jj][r] + bvl;
                if (dores) v += b2f(res[off]);
                C[off] = f2b(v);
                if (doqp) {
                    const int row = row0 + r;
                    const float pv = (col < 128)
                        ? ce[(row & 127) * 128 + col]
                        : re[(row >> 7) * 128 + (col - 128)];
                    C2[(size_t)row * 256 + col] = f2b(v + pv);
                }
            }
        }
    }
}

// ---------------------------------------------------------------------------
// qv core: fp32 [K][NQ] A + K-SPLIT 192-col B panel (25.6 KB LDS) +
// distance-4 A prefetch (5-buffer rotating file).
// ---------------------------------------------------------------------------
__device__ __forceinline__ void gcore_qv(
    bf16* __restrict__ Bs,
    const float* __restrict__ A, const bf16* __restrict__ Bgl,
    const float* __restrict__ bias,
    const float* __restrict__ ce, const float* __restrict__ re,
    bf16* __restrict__ C, bf16* __restrict__ C2,
    int n0, int m0)
{
    constexpr int K = 384, LDB = 192 + 8;

    const int t    = threadIdx.x;
    const int lane = t & 63;
    const int wid  = t >> 6;
    const int lr   = lane & 15;
    const int lg   = lane >> 4;

    const int rowb = m0 + wid * 16 + lr;

    float fa[5][8];
    auto loadA = [&](float f[8], int s) {
        const int k0 = s * 32 + lg * 8;
#pragma unroll
        for (int j = 0; j < 8; ++j)
            f[j] = A[(size_t)(k0 + j) * NQ + rowb];
    };
    auto stageB = [&](int h) {
#pragma unroll
        for (int c = 0; c < 6; ++c) {
            const int id  = c * 256 + t;
            const int row = id / 24;
            const int kc  = id % 24;
            *(int4*)&Bs[row * LDB + kc * 8] =
                *(const int4*)&Bgl[(size_t)row * K + h * 192 + kc * 8];
        }
    };

    loadA(fa[0], 0);
    loadA(fa[1], 1);
    loadA(fa[2], 2);
    loadA(fa[3], 3);
    stageB(0);
    __syncthreads();

    f32x4 acc[4];
#pragma unroll
    for (int j = 0; j < 4; ++j) { f32x4 z = {0.f, 0.f, 0.f, 0.f}; acc[j] = z; }

    bf16x8 bcur[4], bnxt[4];
#pragma unroll
    for (int jj = 0; jj < 4; ++jj)
        bcur[jj] = *(const bf16x8*)&Bs[(jj * 16 + lr) * LDB + lg * 8];

#pragma unroll
    for (int s = 0; s < 12; ++s) {
        const int sh = s % 6;
        if (s + 4 < 12) loadA(fa[(s + 4) % 5], s + 4);
        if (sh < 5) {
#pragma unroll
            for (int jj = 0; jj < 4; ++jj)
                bnxt[jj] = *(const bf16x8*)&Bs[(jj * 16 + lr) * LDB + (sh + 1) * 32 + lg * 8];
        }
        {
            const bf16x8 af = pack8(fa[s % 5]);
#pragma unroll
            for (int jj = 0; jj < 4; ++jj)
                acc[jj] = __builtin_amdgcn_mfma_f32_16x16x32_bf16(
                    af, bcur[jj], acc[jj], 0, 0, 0);
        }
        if (sh == 5 && s < 11) {
            __syncthreads();
            stageB(1);
            __syncthreads();
#pragma unroll
            for (int jj = 0; jj < 4; ++jj)
                bcur[jj] = *(const bf16x8*)&Bs[(jj * 16 + lr) * LDB + lg * 8];
        } else {
#pragma unroll
            for (int jj = 0; jj < 4; ++jj) bcur[jj] = bnxt[jj];
        }
    }

    const bool doqp = C2 != nullptr;
#pragma unroll
    for (int jj = 0; jj < 4; ++jj) {
        const int row0 = m0 + wid * 16 + lg * 4;
        const int col  = n0 + jj * 16 + lr;
        const float bvl = bias[col];
#pragma unroll
        for (int r = 0; r < 4; ++r) {
            const size_t off = (size_t)(row0 + r) * 256 + col;
            float v = acc[jj][r] + bvl;
            C[off] = f2b(v);
            if (doqp) {
                const int row = row0 + r;
                const float pv = (col < 128)
                    ? ce[(row & 127) * 128 + col]
                    : re[(row >> 7) * 128 + (col - 128)];
                C2[off] = f2b(v + pv);
            }
        }
    }
}

// generic: grid = (N/64, M/(MW*64)); XCD-swizzled; NF=4
template<int MW, int KS>
__global__ __launch_bounds__(256)
void gmm_std(const bf16* __restrict__ A, const bf16* __restrict__ B,
             const float* __restrict__ bias, const bf16* __restrict__ res,
             const float* __restrict__ ce, const float* __restrict__ re,
             bf16* __restrict__ C, bf16* __restrict__ C2, int N)
{
    __shared__ bf16 Bs[64 * (KS * 32 + 8)];
    int sx, sy;
    xcd_map(sx, sy);
    const int n0 = sx * 64;
    gcore<MW, 4, KS>(Bs, A, B + (size_t)n0 * (KS * 32), bias, res, ce, re, C, C2,
                     N, n0, sy * (MW * 64));
}

// q-proj (x<4, writes QA and QPb = QA+pos) / v-proj (x>=4); fp32 A, K-split panel
__global__ __launch_bounds__(256)
void gmm_qv(const float* __restrict__ Qf, const bf16* __restrict__ WQ,
            const float* __restrict__ BQ, bf16* __restrict__ QA, bf16* __restrict__ QPb,
            const float* __restrict__ Vf, const bf16* __restrict__ WV,
            const float* __restrict__ BV, bf16* __restrict__ V,
            const float* __restrict__ ce, const float* __restrict__ re)
{
    __shared__ bf16 Bs[64 * (192 + 8)];
    int sx, sy;
    xcd_map(sx, sy);
    const int m0 = sy * 64;
    if (sx < 4) {
        const int n0 = sx * 64;
        gcore_qv(Bs, Qf, WQ + (size_t)n0 * 384, BQ, ce, re, QA, QPb, n0, m0);
    } else {
        const int n0 = (sx - 4) * 64;
        gcore_qv(Bs, Vf, WV + (size_t)n0 * 384, BV, nullptr, nullptr, V, nullptr, n0, m0);
    }
}

// vp for layers 0..2 only (oa is fused into the sampler now); MW=1, grid (12, 256)
__global__ __launch_bounds__(256)
void gmm_vpall(const bf16* __restrict__ V, const bf16* __restrict__ WVP,
               const float* __restrict__ vp_b, bf16* __restrict__ VP)
{
    __shared__ bf16 Bs[64 * (256 + 8)];
    int sx, sy;
    xcd_map(sx, sy);
    const int m0 = sy * 64;
    const int layer = sx >> 2;
    const int nloc  = (sx & 3) * 64;
    gcore<1, 4, 8>(Bs, V, WVP + (size_t)sx * 64 * 256,
                   vp_b + layer * 256, nullptr, nullptr, nullptr,
                   VP + (size_t)layer * NQ * 256, nullptr, 256, nloc, m0);
}

// final GEMM (K=64, N=384) with fused fp32 transposed store
__global__ __launch_bounds__(256)
void gmm_out(const bf16* __restrict__ A, const bf16* __restrict__ B,
             const float* __restrict__ bias, float* __restrict__ out)
{
    constexpr int KS = 2, K = 64, LDB = K + 8;
    __shared__ bf16 Bs[64 * LDB];
    int sx, sy;
    xcd_map(sx, sy);
    const int n0 = sx * 64;
    const int m0 = sy * 64;

    const int t    = threadIdx.x;
    const int lane = t & 63;
    const int wid  = t >> 6;
    const int lr   = lane & 15;
    const int lg   = lane >> 4;

    const bf16* Ab = A + (size_t)(m0 + wid * 16 + lr) * K + lg * 8;
    const bf16* Bb = B + (size_t)n0 * K;

    bf16x8 af0 = *(const bf16x8*)&Ab[0];
    bf16x8 af1 = *(const bf16x8*)&Ab[32];

#pragma unroll
    for (int c = 0; c < 2; ++c) {
        const int id  = c * 256 + t;
        const int row = id >> 3, kc = id & 7;
        *(int4*)&Bs[row * LDB + kc * 8] = *(const int4*)&Bb[(size_t)row * K + kc * 8];
    }
    __syncthreads();

    f32x4 acc[4];
#pragma unroll
    for (int j = 0; j < 4; ++j) { f32x4 z = {0.f, 0.f, 0.f, 0.f}; acc[j] = z; }

#pragma unroll
    for (int s = 0; s < KS; ++s) {
        const bf16x8 af = s == 0 ? af0 : af1;
#pragma unroll
        for (int jj = 0; jj < 4; ++jj) {
            const bf16x8 bf = *(const bf16x8*)&Bs[(jj * 16 + lr) * LDB + s * 32 + lg * 8];
            acc[jj] = __builtin_amdgcn_mfma_f32_16x16x32_bf16(af, bf, acc[jj], 0, 0, 0);
        }
    }

    const int row0 = m0 + wid * 16 + lg * 4;
#pragma unroll
    for (int jj = 0; jj < 4; ++jj) {
        const int col = n0 + jj * 16 + lr;
        const float bvl = bias[col];
        float4 o;
        o.x = acc[jj][0] + bvl;
        o.y = acc[jj][1] + bvl;
        o.z = acc[jj][2] + bvl;
        o.w = acc[jj][3] + bvl;
        *(float4*)&out[(size_t)col * NQ + row0] = o;
    }
}

// ---------------------------------------------------------------------------
// LDS B-panel core with fused LayerNorm+ReLU (MLP layers; full-width N)
// ---------------------------------------------------------------------------
template<int NF, int KS>
__device__ __forceinline__ void gcore_ln(
    bf16* __restrict__ Bs,
    const bf16* __restrict__ A, const bf16* __restrict__ Bgl,
    const float* __restrict__ bias, bf16* __restrict__ C,
    const float* __restrict__ lng, const float* __restrict__ lnb,
    int N, int m0)
{
    constexpr int K    = KS * 32;
    constexpr int LDB  = K + 8;
    constexpr int NPAN = NF * 16;

    const int t    = threadIdx.x;
    const int lane = t & 63;
    const int wid  = t >> 6;
    const int lr   = lane & 15;
    const int lg   = lane >> 4;

#pragma unroll
    for (int c = 0; c < NF * KS / 4; ++c) {
        const int id  = c * 256 + t;
        const int row = id / (KS * 4);
        const int kc  = id % (KS * 4);
        *(int4*)&Bs[row * LDB + kc * 8] = *(const int4*)&Bgl[(size_t)row * K + kc * 8];
    }
    __syncthreads();

    f32x4 acc[NF];
#pragma unroll
    for (int j = 0; j < NF; ++j) { f32x4 z = {0.f, 0.f, 0.f, 0.f}; acc[j] = z; }

    const bf16* Ab = A + (size_t)(m0 + wid * 16 + lr) * K + lg * 8;

#pragma unroll
    for (int s = 0; s < KS; ++s) {
        bf16x8 af = *(const bf16x8*)&Ab[s * 32];
#pragma unroll
        for (int jj = 0; jj < NF; ++jj) {
            const bf16x8 bf = *(const bf16x8*)&Bs[(jj * 16 + lr) * LDB + s * 32 + lg * 8];
            acc[jj] = __builtin_amdgcn_mfma_f32_16x16x32_bf16(af, bf, acc[jj], 0, 0, 0);
        }
    }

    float bvl[NF], gv[NF], bb[NF];
#pragma unroll
    for (int jj = 0; jj < NF; ++jj) {
        const int col = jj * 16 + lr;
        bvl[jj] = bias[col]; gv[jj] = lng[col]; bb[jj] = lnb[col];
    }
#pragma unroll
    for (int r = 0; r < 4; ++r) {
        float v[NF];
        float s = 0.f;
#pragma unroll
        for (int jj = 0; jj < NF; ++jj) { v[jj] = acc[jj][r] + bvl[jj]; s += v[jj]; }
        s += __shfl_xor(s, 1); s += __shfl_xor(s, 2);
        s += __shfl_xor(s, 4); s += __shfl_xor(s, 8);
        const float mu = s * (1.f / NPAN);
        float vs = 0.f;
#pragma unroll
        for (int jj = 0; jj < NF; ++jj) { const float d = v[jj] - mu; vs += d * d; }
        vs += __shfl_xor(vs, 1); vs += __shfl_xor(vs, 2);
        vs += __shfl_xor(vs, 4); vs += __shfl_xor(vs, 8);
        const float rstd = rsqrtf(vs * (1.f / NPAN) + 1e-5f);
        const int row = m0 + wid * 16 + lg * 4 + r;
#pragma unroll
        for (int jj = 0; jj < NF; ++jj) {
            const float o = (v[jj] - mu) * rstd * gv[jj] + bb[jj];
            C[(size_t)row * N + jj * 16 + lr] = f2b(fmaxf(o, 0.f));
        }
    }
}

__global__ __launch_bounds__(256)
void gmm_mlp1(const bf16* __restrict__ A, const bf16* __restrict__ B,
              const float* __restrict__ bias, bf16* __restrict__ C,
              const float* __restrict__ g, const float* __restrict__ b)
{
    __shared__ bf16 Bs[128 * (256 + 8)];
    gcore_ln<8, 8>(Bs, A, B, bias, C, g, b, 128, blockIdx.y * 64);
}

__global__ __launch_bounds__(256)
void gmm_mlp2(const bf16* __restrict__ A, const bf16* __restrict__ B,
              const float* __restrict__ bias, bf16* __restrict__ C,
              const float* __restrict__ g, const float* __restrict__ b)
{
    __shared__ bf16 Bs[64 * (128 + 8)];
    gcore_ln<4, 4>(Bs, A, B, bias, C, g, b, 64, blockIdx.y * 64);
}

// ---------------------------------------------------------------------------
// MERGED prep kernel -- WEIGHTS ONLY.
// ---------------------------------------------------------------------------
__global__ __launch_bounds__(256)
void prep_all(const float* __restrict__ vp_w, const float* __restrict__ op_w,
              const float* __restrict__ off_w, const float* __restrict__ aw_w,
              const float* __restrict__ off_b, const float* __restrict__ aw_b,
              const float* __restrict__ w1, const float* __restrict__ w2,
              const float* __restrict__ w3,
              bf16* __restrict__ WVP, bf16* __restrict__ WOP, bf16* __restrict__ WOA,
              bf16* __restrict__ WM1, bf16* __restrict__ WM2, bf16* __restrict__ WM3,
              float* __restrict__ OAB,
              const float* __restrict__ cqw, const float* __restrict__ cqb,
              const float* __restrict__ cvw, const float* __restrict__ cvb,
              const float* __restrict__ lqw, const float* __restrict__ lqb,
              const float* __restrict__ lvw, const float* __restrict__ lvb,
              bf16* __restrict__ WQc, bf16* __restrict__ WVc,
              float* __restrict__ BQc, float* __restrict__ BVc)
{
    __shared__ float tile[64][65];
    const int b = blockIdx.x;
    const int t = threadIdx.x;
    const int tr  = t >> 4;
    const int tc4 = (t & 15) * 4;

    if (b < 176) {
        const int ti = b;
        const float* src; bf16* dst; int K, N, k0, n0, Nt;
        if (ti < 64)       { const int l = ti >> 4, r = ti & 15; src = vp_w + l * 65536; dst = WVP + l * 65536; K = 256; N = 256; k0 = (r >> 2) * 64; n0 = (r & 3) * 64; Nt = 64; }
        else if (ti < 128) { const int l = (ti - 64) >> 4, r = (ti - 64) & 15; src = op_w + l * 65536; dst = WOP + l * 65536; K = 256; N = 256; k0 = (r >> 2) * 64; n0 = (r & 3) * 64; Nt = 64; }
        else if (ti < 144) { const int l = (ti - 128) >> 2, r = (ti - 128) & 3; src = off_w + l * 16384; dst = WOA + l * 32768; K = 256; N = 64; k0 = r * 64; n0 = 0; Nt = 64; }
        else if (ti < 160) { const int l = (ti - 144) >> 2, r = (ti - 144) & 3; src = aw_w + l * 8192; dst = WOA + l * 32768 + 16384; K = 256; N = 32; k0 = r * 64; n0 = 0; Nt = 32; }
        else if (ti < 168) { const int r = ti - 160; src = w1; dst = WM1; K = 256; N = 128; k0 = (r >> 1) * 64; n0 = (r & 1) * 64; Nt = 64; }
        else if (ti < 170) { const int r = ti - 168; src = w2; dst = WM2; K = 128; N = 64; k0 = r * 64; n0 = 0; Nt = 64; }
        else               { const int r = ti - 170; src = w3; dst = WM3; K = 64; N = 384; k0 = 0; n0 = r * 64; Nt = 64; }
#pragma unroll
        for (int i = 0; i < 4; ++i) {
            const int k = i * 16 + tr;
            if (tc4 < Nt) {
                const float4 vv = *(const float4*)&src[(size_t)(k0 + k) * N + n0 + tc4];
                tile[k][tc4 + 0] = vv.x; tile[k][tc4 + 1] = vv.y;
                tile[k][tc4 + 2] = vv.z; tile[k][tc4 + 3] = vv.w;
            }
        }
        __syncthreads();
#pragma unroll
        for (int i = 0; i < 4; ++i) {
            const int n = i * 16 + tr;
            if (n < Nt) {
                ushort4 o;
                o.x = f2bb(tile[tc4 + 0][n]); o.y = f2bb(tile[tc4 + 1][n]);
                o.z = f2bb(tile[tc4 + 2][n]); o.w = f2bb(tile[tc4 + 3][n]);
                *(ushort4*)&dst[(size_t)(n0 + n) * K + k0 + tc4] = o;
            }
        }
        return;
    }
    if (b < 192) {
        const int z0 = (b - 176) * 2048 + t * 8;
        const int l = z0 >> 13, r = z0 & 8191;
        bf16x8 zz = {0, 0, 0, 0, 0, 0, 0, 0};
        *(bf16x8*)&WOA[(size_t)l * 32768 + 24576 + r] = zz;
        return;
    }
    if (b < 961) {
        const int bb = b - 192;
        if (bb < 768) {
            const bool isq = bb < 384;
            const float* cw = isq ? cqw : cvw;
            const float* lw = isq ? lqw : lvw;
            bf16* W = isq ? WQc : WVc;
            const int idx = (bb % 384) * 256 + t;
            const int n = idx / 384, c = idx % 384;
            float s = 0.f;
            for (int d = 0; d < 256; ++d)
                s = fmaf(cw[d * 384 + c], lw[d * 256 + n], s);
            W[idx] = f2b(s);
        } else {
            const int n = t;
            float sq = lqb[n], sv = lvb[n];
            for (int d = 0; d < 256; ++d) {
                sq = fmaf(cqb[d], lqw[d * 256 + n], sq);
                sv = fmaf(cvb[d], lvw[d * 256 + n], sv);
            }
            BQc[n] = sq; BVc[n] = sv;
        }
        return;
    }
    {
        const int idx = (b - 961) * 256 + t;
        if (idx < 512) {
            const int l = idx >> 7, r = idx & 127;
            OAB[idx] = (r < 64) ? off_b[l * 64 + r] : (r < 96 ? aw_b[l * 32 + r - 64] : 0.f);
        }
    }
}

// ---------------------------------------------------------------------------
// FUSED oa-GEMM + softmax + bilinear sampling. 512 thr, 16 pixels per block.
// Phase 1: oa rows via MFMA (wave w owns n-frag w of N=128; A = QPb 16 rows,
//          K = 256) -> 4KB LDS tile. Removes the separate oa-GEMM launch and
//          the OA global round-trip (the oa output's ONLY consumer is here).
// Phase 2: the round-3 sampler body, offsets/logits read from LDS.
// ---------------------------------------------------------------------------
__global__ __launch_bounds__(512)
void sample_fused(const bf16* __restrict__ val, const bf16* __restrict__ QPb,
                  const bf16* __restrict__ Boa, const float* __restrict__ boa,
                  bf16* __restrict__ out)
{
    __shared__ bf16 oa_s[16][136];   // row stride 272B = 16B-aligned
    const int tid = threadIdx.x;
    const int p0 = blockIdx.x * 16;

    {   // phase 1: oa[16][128] = QPb[p0..p0+15] @ Boa^T + boa
        const int lane = tid & 63;
        const int w    = tid >> 6;          // 8 waves -> n-frag w
        const int lr   = lane & 15;
        const int lg   = lane >> 4;
        const bf16* Ab = QPb + (size_t)(p0 + lr) * 256 + lg * 8;
        const bf16* Bb = Boa + (size_t)(w * 16 + lr) * 256 + lg * 8;
        f32x4 acc = {0.f, 0.f, 0.f, 0.f};
#pragma unroll
        for (int s = 0; s < 8; ++s) {
            const bf16x8 af = *(const bf16x8*)&Ab[s * 32];
            const bf16x8 bf = *(const bf16x8*)&Bb[s * 32];
            acc = __builtin_amdgcn_mfma_f32_16x16x32_bf16(af, bf, acc, 0, 0, 0);
        }
        const int col = w * 16 + lr;        // C layout: col=lane&15, row=lg*4+r
        const float bvl = boa[col];
#pragma unroll
        for (int r = 0; r < 4; ++r)
            oa_s[lg * 4 + r][col] = f2b(acc[r] + bvl);
    }
    __syncthreads();

    // phase 2: 512 slots = 16 pixels x 32 threads
    const int pixl = tid >> 5;
    const int thr  = tid & 31;
    const int pix  = p0 + pixl;
    const int head = thr >> 2;
    const int c0   = thr * 8;
    const float fx = (float)(pix & 127);
    const float fy = (float)(pix >> 7);
    const unsigned short* oap = (const unsigned short*)&oa_s[pixl][0];
    const bf16x8 offs = *(const bf16x8*)&oap[head * 8];
    const ushort4 lg4 = *(const ushort4*)&oap[64 + head * 4];
    const float l0 = us2f(lg4.x), l1 = us2f(lg4.y), l2 = us2f(lg4.z), l3 = us2f(lg4.w);
    const float mx = fmaxf(fmaxf(l0, l1), fmaxf(l2, l3));
    const float e0 = __expf(l0 - mx), e1 = __expf(l1 - mx);
    const float e2 = __expf(l2 - mx), e3 = __expf(l3 - mx);
    const float inv = 1.f / (e0 + e1 + e2 + e3);
    const float aw4[4] = {e0 * inv, e1 * inv, e2 * inv, e3 * inv};

    float acc[8];
#pragma unroll
    for (int c = 0; c < 8; ++c) acc[c] = 0.f;

#pragma unroll
    for (int p = 0; p < 4; ++p) {
        const float x = fx + us2f((unsigned short)offs[p * 2 + 0]);
        const float y = fy + us2f((unsigned short)offs[p * 2 + 1]);
        const float x0f = floorf(x), y0f = floorf(y);
        const float lx = x - x0f, ly = y - y0f;
        const int x0 = (int)x0f, y0 = (int)y0f;
        const float a = aw4[p];
        const float wc[4] = {(1.f - lx) * (1.f - ly) * a, lx * (1.f - ly) * a,
                             (1.f - lx) * ly * a,         lx * ly * a};
        const int xs[4] = {x0, x0 + 1, x0, x0 + 1};
        const int ys[4] = {y0, y0, y0 + 1, y0 + 1};
#pragma unroll
        for (int k = 0; k < 4; ++k) {
            if ((unsigned)ys[k] < 128u && (unsigned)xs[k] < 128u) {
                const bf16x8 v = *(const bf16x8*)&val[(size_t)((ys[k] << 7) + xs[k]) * 256 + c0];
                const float w = wc[k];
#pragma unroll
                for (int c = 0; c < 8; ++c)
                    acc[c] = fmaf(us2f((unsigned short)v[c]), w, acc[c]);
            }
        }
    }
    bf16x8 o;
#pragma unroll
    for (int c = 0; c < 8; ++c) o[c] = (short)f2bb(acc[c]);
    *(bf16x8*)&out[(size_t)pix * 256 + c0] = o;
}

extern "C" void kernel_launch(void* const* d_in, const int* in_sizes, int n_in,
                              void* d_out, int out_size, void* d_ws, size_t ws_size,
                              hipStream_t stream)
{
    const float* query     = (const float*)d_in[0];
    const float* value     = (const float*)d_in[1];
    const float* conv_q_w  = (const float*)d_in[2];
    const float* conv_q_b  = (const float*)d_in[3];
    const float* conv_v_w  = (const float*)d_in[4];
    const float* conv_v_b  = (const float*)d_in[5];
    const float* row_embed = (const float*)d_in[6];
    const float* col_embed = (const float*)d_in[7];
    const float* lin_q_w   = (const float*)d_in[8];
    const float* lin_q_b   = (const float*)d_in[9];
    const float* lin_v_w   = (const float*)d_in[10];
    const float* lin_v_b   = (const float*)d_in[11];
    const float* off_w     = (const float*)d_in[12];
    const float* off_b     = (const float*)d_in[13];
    const float* aw_w      = (const float*)d_in[14];
    const float* aw_b      = (const float*)d_in[15];
    const float* vp_w      = (const float*)d_in[16];
    const float* vp_b      = (const float*)d_in[17];
    const float* op_w      = (const float*)d_in[18];
    const float* op_b      = (const float*)d_in[19];
    const float* out_w1    = (const float*)d_in[20];
    const float* out_b1    = (const float*)d_in[21];
    const float* ln1_g     = (const float*)d_in[22];
    const float* ln1_b     = (const float*)d_in[23];
    const float* out_w2    = (const float*)d_in[24];
    const float* out_b2    = (const float*)d_in[25];
    const float* ln2_g     = (const float*)d_in[26];
    const float* ln2_b     = (const float*)d_in[27];
    const float* out_w3    = (const float*)d_in[28];
    const float* out_b3    = (const float*)d_in[29];

    bf16* w = (bf16*)d_ws;
    auto alloc = [&](size_t n) { bf16* p = w; w += n; return p; };
    bf16* QA  = alloc((size_t)NQ * 256);
    bf16* QB  = alloc((size_t)NQ * 256);
    bf16* QPb = alloc((size_t)NQ * 256);
    bf16* V   = alloc((size_t)NQ * 256);
    bf16* T1  = alloc((size_t)NQ * 256);
    bf16* T2  = alloc((size_t)NQ * 256);
    bf16* VP  = alloc((size_t)3 * NQ * 256);   // vp outputs, layers 0..2
    bf16* WQc = alloc(256 * 384);
    bf16* WVc = alloc(256 * 384);
    bf16* WVP = alloc(4 * 256 * 256);
    bf16* WOP = alloc(4 * 256 * 256);
    bf16* WOA = alloc(4 * 128 * 256);
    bf16* WM1 = alloc(128 * 256);
    bf16* WM2 = alloc(64 * 128);
    bf16* WM3 = alloc(384 * 64);
    float* fp = (float*)w;
    float* BQc = fp; fp += 256;
    float* BVc = fp; fp += 256;
    float* OAB = fp; fp += 512;

    const dim3 blk(256);

    prep_all<<<963, blk, 0, stream>>>(
        vp_w, op_w, off_w, aw_w, off_b, aw_b, out_w1, out_w2, out_w3,
        WVP, WOP, WOA, WM1, WM2, WM3, OAB,
        conv_q_w, conv_q_b, conv_v_w, conv_v_b,
        lin_q_w, lin_q_b, lin_v_w, lin_v_b,
        WQc, WVc, BQc, BVc);

    gmm_qv<<<dim3(8, 256), blk, 0, stream>>>(
        query, WQc, BQc, QA, QPb, value, WVc, BVc, V, col_embed, row_embed);
    gmm_vpall<<<dim3(12, 256), blk, 0, stream>>>(V, WVP, vp_b, VP);

    bf16* cur = QA;
    bf16* nxt = QB;
    for (int i = 0; i < 4; ++i) {
        const bf16* valbuf;
        if (i < 3) {
            valbuf = VP + (size_t)i * NQ * 256;
        } else {
            // self layer: vp from cur
            gmm_std<1, 8><<<dim3(4, 256), blk, 0, stream>>>(
                cur, WVP + (size_t)3 * 65536, vp_b + 3 * 256, nullptr,
                nullptr, nullptr, T2, nullptr, 256);
            valbuf = T2;
        }
        sample_fused<<<1024, dim3(512), 0, stream>>>(
            valbuf, QPb, WOA + (size_t)i * 32768, OAB + i * 128, T1);
        gmm_std<1, 8><<<dim3(4, 256), blk, 0, stream>>>(
            T1, WOP + (size_t)i * 65536, op_b + i * 256, cur,
            col_embed, row_embed, nxt, QPb, 256);
        bf16* tmp = cur; cur = nxt; nxt = tmp;
    }

    // output MLP (LN+ReLU fused); final GEMM stores fp32 transposed directly
    gmm_mlp1<<<dim3(1, 256), blk, 0, stream>>>(cur, WM1, out_b1, T1, ln1_g, ln1_b);
    gmm_mlp2<<<dim3(1, 256), blk, 0, stream>>>(T1, WM2, out_b2, T2, ln2_g, ln2_b);
    gmm_out<<<dim3(6, 256), blk, 0, stream>>>(T2, WM3, out_b3, (float*)d_out);
}

// Round 24
// 210.972 us; speedup vs baseline: 1.2202x; 1.2202x over previous
//
#include <hip/hip_runtime.h>
#include <hip/hip_bf16.h>

#define NQ   16384
#define DIM  256

using bf16 = __hip_bfloat16;
using bf16x8 = __attribute__((ext_vector_type(8))) short;
using f32x4  = __attribute__((ext_vector_type(4))) float;

__device__ __forceinline__ float b2f(bf16 x) { return __bfloat162float(x); }
__device__ __forceinline__ bf16  f2b(float x) { return __float2bfloat16(x); }
__device__ __forceinline__ unsigned short f2bb(float x) {
    bf16 h = __float2bfloat16(x);
    return *(unsigned short*)&h;
}
__device__ __forceinline__ float us2f(unsigned short u) {
    unsigned int x = ((unsigned int)u) << 16;
    return __builtin_bit_cast(float, x);
}
__device__ __forceinline__ bf16x8 pack8(const float* f) {
    bf16x8 r;
#pragma unroll
    for (int j = 0; j < 8; ++j) r[j] = (short)f2bb(f[j]);
    return r;
}

// Bijective XCD-aware block remap (m204)
__device__ __forceinline__ void xcd_map(int& sx, int& sy)
{
    const int gx  = gridDim.x;
    const int nwg = gridDim.x * gridDim.y;
    const int bid = blockIdx.y * gx + blockIdx.x;
    const int q = nwg >> 3, r = nwg & 7;
    const int xcd = bid & 7, sl = bid >> 3;
    const int s = (xcd < r ? xcd * (q + 1) : r * (q + 1) + (xcd - r) * q) + sl;
    sx = s % gx;
    sy = s / gx;
}

// ---------------------------------------------------------------------------
// Barrier-free B-panel GEMM core, M-split, SOFTWARE-PIPELINED.
// C[M,N] = A[M,K] @ B[N,K]^T + bias (+res) (+QP: C2 = C + pos(row,col)).
// ---------------------------------------------------------------------------
template<int MW, int NF, int KS>
__device__ __forceinline__ void gcore(
    bf16* __restrict__ Bs,
    const bf16* __restrict__ A, const bf16* __restrict__ Bgl,
    const float* __restrict__ bias, const bf16* __restrict__ res,
    const float* __restrict__ ce, const float* __restrict__ re,
    bf16* __restrict__ C, bf16* __restrict__ C2,
    int N, int n0, int m0)
{
    constexpr int K   = KS * 32;
    constexpr int LDB = K + 8;

    const int t    = threadIdx.x;
    const int lane = t & 63;
    const int wid  = t >> 6;
    const int lr   = lane & 15;
    const int lg   = lane >> 4;

    const bf16* Ab = A + (size_t)(m0 + wid * MW * 16 + lr) * K + lg * 8;

    bf16x8 af0[MW], af1[MW], af2[MW];
#pragma unroll
    for (int mi = 0; mi < MW; ++mi)
        af0[mi] = *(const bf16x8*)&Ab[(size_t)(mi * 16) * K + 0];
    if (KS > 1) {
#pragma unroll
        for (int mi = 0; mi < MW; ++mi)
            af1[mi] = *(const bf16x8*)&Ab[(size_t)(mi * 16) * K + 32];
    }

#pragma unroll
    for (int c = 0; c < NF * KS / 4; ++c) {
        const int id  = c * 256 + t;
        const int row = id / (KS * 4);
        const int kc  = id % (KS * 4);
        *(int4*)&Bs[row * LDB + kc * 8] = *(const int4*)&Bgl[(size_t)row * K + kc * 8];
    }
    __syncthreads();

    f32x4 acc[MW][NF];
#pragma unroll
    for (int i = 0; i < MW; ++i)
#pragma unroll
        for (int j = 0; j < NF; ++j) {
            f32x4 z = {0.f, 0.f, 0.f, 0.f};
            acc[i][j] = z;
        }

    bf16x8 bcur[NF], bnxt[NF];
#pragma unroll
    for (int jj = 0; jj < NF; ++jj)
        bcur[jj] = *(const bf16x8*)&Bs[(jj * 16 + lr) * LDB + lg * 8];

#pragma unroll
    for (int s = 0; s < KS; ++s) {
        if (s + 2 < KS) {
#pragma unroll
            for (int mi = 0; mi < MW; ++mi)
                af2[mi] = *(const bf16x8*)&Ab[(size_t)(mi * 16) * K + (s + 2) * 32];
        }
        if (s + 1 < KS) {
#pragma unroll
            for (int jj = 0; jj < NF; ++jj)
                bnxt[jj] = *(const bf16x8*)&Bs[(jj * 16 + lr) * LDB + (s + 1) * 32 + lg * 8];
        }
#pragma unroll
        for (int mi = 0; mi < MW; ++mi)
#pragma unroll
            for (int jj = 0; jj < NF; ++jj)
                acc[mi][jj] = __builtin_amdgcn_mfma_f32_16x16x32_bf16(
                    af0[mi], bcur[jj], acc[mi][jj], 0, 0, 0);
#pragma unroll
        for (int mi = 0; mi < MW; ++mi) { af0[mi] = af1[mi]; af1[mi] = af2[mi]; }
#pragma unroll
        for (int jj = 0; jj < NF; ++jj) bcur[jj] = bnxt[jj];
    }

    const bool dores = res != nullptr;
    const bool doqp  = C2 != nullptr;
    // C/D layout: col = lane&15, row = (lane>>4)*4 + reg
#pragma unroll
    for (int mi = 0; mi < MW; ++mi) {
#pragma unroll
        for (int jj = 0; jj < NF; ++jj) {
            const int row0 = m0 + wid * MW * 16 + mi * 16 + lg * 4;
            const int col  = n0 + jj * 16 + lr;
            const float bvl = bias[col];
#pragma unroll
            for (int r = 0; r < 4; ++r) {
                const size_t off = (size_t)(row0 + r) * N + col;
                float v = acc[mi][jj][r] + bvl;
                if (dores) v += b2f(res[off]);
                C[off] = f2b(v);
                if (doqp) {
                    const int row = row0 + r;
                    const float pv = (col < 128)
                        ? ce[(row & 127) * 128 + col]
                        : re[(row >> 7) * 128 + (col - 128)];
                    C2[(size_t)row * 256 + col] = f2b(v + pv);
                }
            }
        }
    }
}

// ---------------------------------------------------------------------------
// qv core: fp32 [K][NQ] A + K-SPLIT 192-col B panel (25.6 KB LDS) +
// distance-4 A prefetch (5-buffer rotating file).
// ---------------------------------------------------------------------------
__device__ __forceinline__ void gcore_qv(
    bf16* __restrict__ Bs,
    const float* __restrict__ A, const bf16* __restrict__ Bgl,
    const float* __restrict__ bias,
    const float* __restrict__ ce, const float* __restrict__ re,
    bf16* __restrict__ C, bf16* __restrict__ C2,
    int n0, int m0)
{
    constexpr int K = 384, LDB = 192 + 8;

    const int t    = threadIdx.x;
    const int lane = t & 63;
    const int wid  = t >> 6;
    const int lr   = lane & 15;
    const int lg   = lane >> 4;

    const int rowb = m0 + wid * 16 + lr;

    float fa[5][8];
    auto loadA = [&](float f[8], int s) {
        const int k0 = s * 32 + lg * 8;
#pragma unroll
        for (int j = 0; j < 8; ++j)
            f[j] = A[(size_t)(k0 + j) * NQ + rowb];
    };
    auto stageB = [&](int h) {
#pragma unroll
        for (int c = 0; c < 6; ++c) {
            const int id  = c * 256 + t;
            const int row = id / 24;
            const int kc  = id % 24;
            *(int4*)&Bs[row * LDB + kc * 8] =
                *(const int4*)&Bgl[(size_t)row * K + h * 192 + kc * 8];
        }
    };

    loadA(fa[0], 0);
    loadA(fa[1], 1);
    loadA(fa[2], 2);
    loadA(fa[3], 3);
    stageB(0);
    __syncthreads();

    f32x4 acc[4];
#pragma unroll
    for (int j = 0; j < 4; ++j) { f32x4 z = {0.f, 0.f, 0.f, 0.f}; acc[j] = z; }

    bf16x8 bcur[4], bnxt[4];
#pragma unroll
    for (int jj = 0; jj < 4; ++jj)
        bcur[jj] = *(const bf16x8*)&Bs[(jj * 16 + lr) * LDB + lg * 8];

#pragma unroll
    for (int s = 0; s < 12; ++s) {
        const int sh = s % 6;
        if (s + 4 < 12) loadA(fa[(s + 4) % 5], s + 4);
        if (sh < 5) {
#pragma unroll
            for (int jj = 0; jj < 4; ++jj)
                bnxt[jj] = *(const bf16x8*)&Bs[(jj * 16 + lr) * LDB + (sh + 1) * 32 + lg * 8];
        }
        {
            const bf16x8 af = pack8(fa[s % 5]);
#pragma unroll
            for (int jj = 0; jj < 4; ++jj)
                acc[jj] = __builtin_amdgcn_mfma_f32_16x16x32_bf16(
                    af, bcur[jj], acc[jj], 0, 0, 0);
        }
        if (sh == 5 && s < 11) {
            __syncthreads();
            stageB(1);
            __syncthreads();
#pragma unroll
            for (int jj = 0; jj < 4; ++jj)
                bcur[jj] = *(const bf16x8*)&Bs[(jj * 16 + lr) * LDB + lg * 8];
        } else {
#pragma unroll
            for (int jj = 0; jj < 4; ++jj) bcur[jj] = bnxt[jj];
        }
    }

    const bool doqp = C2 != nullptr;
#pragma unroll
    for (int jj = 0; jj < 4; ++jj) {
        const int row0 = m0 + wid * 16 + lg * 4;
        const int col  = n0 + jj * 16 + lr;
        const float bvl = bias[col];
#pragma unroll
        for (int r = 0; r < 4; ++r) {
            const size_t off = (size_t)(row0 + r) * 256 + col;
            float v = acc[jj][r] + bvl;
            C[off] = f2b(v);
            if (doqp) {
                const int row = row0 + r;
                const float pv = (col < 128)
                    ? ce[(row & 127) * 128 + col]
                    : re[(row >> 7) * 128 + (col - 128)];
                C2[off] = f2b(v + pv);
            }
        }
    }
}

// generic: grid = (N/64, M/(MW*64)); XCD-swizzled; NF=4
template<int MW, int KS>
__global__ __launch_bounds__(256)
void gmm_std(const bf16* __restrict__ A, const bf16* __restrict__ B,
             const float* __restrict__ bias, const bf16* __restrict__ res,
             const float* __restrict__ ce, const float* __restrict__ re,
             bf16* __restrict__ C, bf16* __restrict__ C2, int N)
{
    __shared__ bf16 Bs[64 * (KS * 32 + 8)];
    int sx, sy;
    xcd_map(sx, sy);
    const int n0 = sx * 64;
    gcore<MW, 4, KS>(Bs, A, B + (size_t)n0 * (KS * 32), bias, res, ce, re, C, C2,
                     N, n0, sy * (MW * 64));
}

// q-proj (x<4, writes QA and QPb = QA+pos) / v-proj (x>=4); fp32 A, K-split panel
__global__ __launch_bounds__(256)
void gmm_qv(const float* __restrict__ Qf, const bf16* __restrict__ WQ,
            const float* __restrict__ BQ, bf16* __restrict__ QA, bf16* __restrict__ QPb,
            const float* __restrict__ Vf, const bf16* __restrict__ WV,
            const float* __restrict__ BV, bf16* __restrict__ V,
            const float* __restrict__ ce, const float* __restrict__ re)
{
    __shared__ bf16 Bs[64 * (192 + 8)];
    int sx, sy;
    xcd_map(sx, sy);
    const int m0 = sy * 64;
    if (sx < 4) {
        const int n0 = sx * 64;
        gcore_qv(Bs, Qf, WQ + (size_t)n0 * 384, BQ, ce, re, QA, QPb, n0, m0);
    } else {
        const int n0 = (sx - 4) * 64;
        gcore_qv(Bs, Vf, WV + (size_t)n0 * 384, BV, nullptr, nullptr, V, nullptr, n0, m0);
    }
}

// batched: x<12 -> vp layers 0..2; x>=12 -> layer-0 oa; MW=1, grid (14, 256)
__global__ __launch_bounds__(256)
void gmm_vpall(const bf16* __restrict__ V, const bf16* __restrict__ WVP,
               const float* __restrict__ vp_b, bf16* __restrict__ VP,
               const bf16* __restrict__ QPb, const bf16* __restrict__ Boa,
               const float* __restrict__ boa, bf16* __restrict__ OA)
{
    __shared__ bf16 Bs[64 * (256 + 8)];
    int sx, sy;
    xcd_map(sx, sy);
    const int m0 = sy * 64;
    if (sx < 12) {
        const int layer = sx >> 2;
        const int nloc  = (sx & 3) * 64;
        gcore<1, 4, 8>(Bs, V, WVP + (size_t)sx * 64 * 256,
                       vp_b + layer * 256, nullptr, nullptr, nullptr,
                       VP + (size_t)layer * NQ * 256, nullptr, 256, nloc, m0);
    } else {
        const int n0 = (sx - 12) * 64;
        gcore<1, 4, 8>(Bs, QPb, Boa + (size_t)n0 * 256, boa, nullptr, nullptr, nullptr,
                       OA, nullptr, 128, n0, m0);
    }
}

// layer-3: x<4 -> vp slices from cur (C=T2); x>=4 -> oa slices; MW=1, grid (6,256)
__global__ __launch_bounds__(256)
void gmm_vo3(const bf16* __restrict__ cur, const bf16* __restrict__ Bvp,
             const float* __restrict__ bvp, bf16* __restrict__ T2,
             const bf16* __restrict__ QPb, const bf16* __restrict__ Boa,
             const float* __restrict__ boa, bf16* __restrict__ OA)
{
    __shared__ bf16 Bs[64 * (256 + 8)];
    int sx, sy;
    xcd_map(sx, sy);
    const int m0 = sy * 64;
    if (sx < 4) {
        const int n0 = sx * 64;
        gcore<1, 4, 8>(Bs, cur, Bvp + (size_t)n0 * 256, bvp, nullptr, nullptr, nullptr,
                       T2, nullptr, 256, n0, m0);
    } else {
        const int n0 = (sx - 4) * 64;
        gcore<1, 4, 8>(Bs, QPb, Boa + (size_t)n0 * 256, boa, nullptr, nullptr, nullptr,
                       OA, nullptr, 128, n0, m0);
    }
}

// ---------------------------------------------------------------------------
// FUSED MLP TAIL: mlp1(256->128)+LN+ReLU -> mlp2(128->64)+LN+ReLU ->
// out(64->384) with fp32 transposed store. Row-local end-to-end: block owns
// 64 rows; intermediates live in LDS (h1, h2; still rounded to bf16 so math
// is identical to the separate kernels). B panels staged sequentially into
// one reused LDS buffer. Replaces 3 launches + T1/T2 round-trips.
// ---------------------------------------------------------------------------
__global__ __launch_bounds__(256)
void mlp_tail(const bf16* __restrict__ A,
              const bf16* __restrict__ WM1, const float* __restrict__ b1,
              const float* __restrict__ g1, const float* __restrict__ lb1,
              const bf16* __restrict__ WM2, const float* __restrict__ b2,
              const float* __restrict__ g2, const float* __restrict__ lb2,
              const bf16* __restrict__ WM3, const float* __restrict__ b3,
              float* __restrict__ out)
{
    __shared__ bf16 Bs[128 * 264];      // reused: 128x(256+8) / 64x(128+8) / 384x(64+8)
    __shared__ bf16 h1[64][136];
    __shared__ bf16 h2[64][72];

    const int t    = threadIdx.x;
    const int lane = t & 63;
    const int wid  = t >> 6;
    const int lr   = lane & 15;
    const int lg   = lane >> 4;
    const int m0   = blockIdx.x * 64;

    // ---- stage 1: h1 = relu(ln(A[m0..m0+63] @ WM1^T + b1)) ----
    {
#pragma unroll
        for (int c = 0; c < 16; ++c) {      // 128 rows x 32 int4-chunks (K=256)
            const int id = c * 256 + t, row = id >> 5, kc = id & 31;
            *(int4*)&Bs[row * 264 + kc * 8] = *(const int4*)&WM1[(size_t)row * 256 + kc * 8];
        }
        __syncthreads();
        f32x4 acc[8];
#pragma unroll
        for (int j = 0; j < 8; ++j) { f32x4 z = {0.f, 0.f, 0.f, 0.f}; acc[j] = z; }
        const bf16* Ab = A + (size_t)(m0 + wid * 16 + lr) * 256 + lg * 8;
#pragma unroll
        for (int s = 0; s < 8; ++s) {
            const bf16x8 af = *(const bf16x8*)&Ab[s * 32];
#pragma unroll
            for (int jj = 0; jj < 8; ++jj) {
                const bf16x8 bf = *(const bf16x8*)&Bs[(jj * 16 + lr) * 264 + s * 32 + lg * 8];
                acc[jj] = __builtin_amdgcn_mfma_f32_16x16x32_bf16(af, bf, acc[jj], 0, 0, 0);
            }
        }
        float bvl[8], gv[8], bb[8];
#pragma unroll
        for (int jj = 0; jj < 8; ++jj) {
            const int col = jj * 16 + lr;
            bvl[jj] = b1[col]; gv[jj] = g1[col]; bb[jj] = lb1[col];
        }
#pragma unroll
        for (int r = 0; r < 4; ++r) {
            float v[8];
            float s = 0.f;
#pragma unroll
            for (int jj = 0; jj < 8; ++jj) { v[jj] = acc[jj][r] + bvl[jj]; s += v[jj]; }
            s += __shfl_xor(s, 1); s += __shfl_xor(s, 2);
            s += __shfl_xor(s, 4); s += __shfl_xor(s, 8);
            const float mu = s * (1.f / 128.f);
            float vs = 0.f;
#pragma unroll
            for (int jj = 0; jj < 8; ++jj) { const float d = v[jj] - mu; vs += d * d; }
            vs += __shfl_xor(vs, 1); vs += __shfl_xor(vs, 2);
            vs += __shfl_xor(vs, 4); vs += __shfl_xor(vs, 8);
            const float rstd = rsqrtf(vs * (1.f / 128.f) + 1e-5f);
            const int row = wid * 16 + lg * 4 + r;
#pragma unroll
            for (int jj = 0; jj < 8; ++jj) {
                const float o = (v[jj] - mu) * rstd * gv[jj] + bb[jj];
                h1[row][jj * 16 + lr] = f2b(fmaxf(o, 0.f));
            }
        }
    }
    __syncthreads();

    // ---- stage 2: h2 = relu(ln(h1 @ WM2^T + b2)) ----
    {
#pragma unroll
        for (int c = 0; c < 4; ++c) {       // 64 rows x 16 int4-chunks (K=128)
            const int id = c * 256 + t, row = id >> 4, kc = id & 15;
            *(int4*)&Bs[row * 136 + kc * 8] = *(const int4*)&WM2[(size_t)row * 128 + kc * 8];
        }
        __syncthreads();
        f32x4 acc[4];
#pragma unroll
        for (int j = 0; j < 4; ++j) { f32x4 z = {0.f, 0.f, 0.f, 0.f}; acc[j] = z; }
#pragma unroll
        for (int s = 0; s < 4; ++s) {
            const bf16x8 af = *(const bf16x8*)&h1[wid * 16 + lr][s * 32 + lg * 8];
#pragma unroll
            for (int jj = 0; jj < 4; ++jj) {
                const bf16x8 bf = *(const bf16x8*)&Bs[(jj * 16 + lr) * 136 + s * 32 + lg * 8];
                acc[jj] = __builtin_amdgcn_mfma_f32_16x16x32_bf16(af, bf, acc[jj], 0, 0, 0);
            }
        }
        float bvl[4], gv[4], bb[4];
#pragma unroll
        for (int jj = 0; jj < 4; ++jj) {
            const int col = jj * 16 + lr;
            bvl[jj] = b2[col]; gv[jj] = g2[col]; bb[jj] = lb2[col];
        }
#pragma unroll
        for (int r = 0; r < 4; ++r) {
            float v[4];
            float s = 0.f;
#pragma unroll
            for (int jj = 0; jj < 4; ++jj) { v[jj] = acc[jj][r] + bvl[jj]; s += v[jj]; }
            s += __shfl_xor(s, 1); s += __shfl_xor(s, 2);
            s += __shfl_xor(s, 4); s += __shfl_xor(s, 8);
            const float mu = s * (1.f / 64.f);
            float vs = 0.f;
#pragma unroll
            for (int jj = 0; jj < 4; ++jj) { const float d = v[jj] - mu; vs += d * d; }
            vs += __shfl_xor(vs, 1); vs += __shfl_xor(vs, 2);
            vs += __shfl_xor(vs, 4); vs += __shfl_xor(vs, 8);
            const float rstd = rsqrtf(vs * (1.f / 64.f) + 1e-5f);
            const int row = wid * 16 + lg * 4 + r;
#pragma unroll
            for (int jj = 0; jj < 4; ++jj) {
                const float o = (v[jj] - mu) * rstd * gv[jj] + bb[jj];
                h2[row][jj * 16 + lr] = f2b(fmaxf(o, 0.f));
            }
        }
    }
    __syncthreads();

    // ---- stage 3: out[col][m0+row] = h2 @ WM3^T + b3 (fp32 transposed store) ----
    {
#pragma unroll
        for (int c = 0; c < 12; ++c) {      // 384 rows x 8 int4-chunks (K=64)
            const int id = c * 256 + t, row = id >> 3, kc = id & 7;
            *(int4*)&Bs[row * 72 + kc * 8] = *(const int4*)&WM3[(size_t)row * 64 + kc * 8];
        }
        __syncthreads();
        const bf16x8 af0 = *(const bf16x8*)&h2[wid * 16 + lr][lg * 8];
        const bf16x8 af1 = *(const bf16x8*)&h2[wid * 16 + lr][32 + lg * 8];
        f32x4 acc[24];
#pragma unroll
        for (int j = 0; j < 24; ++j) { f32x4 z = {0.f, 0.f, 0.f, 0.f}; acc[j] = z; }
#pragma unroll
        for (int s = 0; s < 2; ++s) {
            const bf16x8 af = s == 0 ? af0 : af1;
#pragma unroll
            for (int jj = 0; jj < 24; ++jj) {
                const bf16x8 bf = *(const bf16x8*)&Bs[(jj * 16 + lr) * 72 + s * 32 + lg * 8];
                acc[jj] = __builtin_amdgcn_mfma_f32_16x16x32_bf16(af, bf, acc[jj], 0, 0, 0);
            }
        }
        const int row0 = m0 + wid * 16 + lg * 4;
#pragma unroll
        for (int jj = 0; jj < 24; ++jj) {
            const int col = jj * 16 + lr;
            const float bvl = b3[col];
            float4 o;
            o.x = acc[jj][0] + bvl;
            o.y = acc[jj][1] + bvl;
            o.z = acc[jj][2] + bvl;
            o.w = acc[jj][3] + bvl;
            *(float4*)&out[(size_t)col * NQ + row0] = o;
        }
    }
}

// ---------------------------------------------------------------------------
// MERGED prep kernel -- WEIGHTS ONLY.
// ---------------------------------------------------------------------------
__global__ __launch_bounds__(256)
void prep_all(const float* __restrict__ vp_w, const float* __restrict__ op_w,
              const float* __restrict__ off_w, const float* __restrict__ aw_w,
              const float* __restrict__ off_b, const float* __restrict__ aw_b,
              const float* __restrict__ w1, const float* __restrict__ w2,
              const float* __restrict__ w3,
              bf16* __restrict__ WVP, bf16* __restrict__ WOP, bf16* __restrict__ WOA,
              bf16* __restrict__ WM1, bf16* __restrict__ WM2, bf16* __restrict__ WM3,
              float* __restrict__ OAB,
              const float* __restrict__ cqw, const float* __restrict__ cqb,
              const float* __restrict__ cvw, const float* __restrict__ cvb,
              const float* __restrict__ lqw, const float* __restrict__ lqb,
              const float* __restrict__ lvw, const float* __restrict__ lvb,
              bf16* __restrict__ WQc, bf16* __restrict__ WVc,
              float* __restrict__ BQc, float* __restrict__ BVc)
{
    __shared__ float tile[64][65];
    const int b = blockIdx.x;
    const int t = threadIdx.x;
    const int tr  = t >> 4;
    const int tc4 = (t & 15) * 4;

    if (b < 176) {
        const int ti = b;
        const float* src; bf16* dst; int K, N, k0, n0, Nt;
        if (ti < 64)       { const int l = ti >> 4, r = ti & 15; src = vp_w + l * 65536; dst = WVP + l * 65536; K = 256; N = 256; k0 = (r >> 2) * 64; n0 = (r & 3) * 64; Nt = 64; }
        else if (ti < 128) { const int l = (ti - 64) >> 4, r = (ti - 64) & 15; src = op_w + l * 65536; dst = WOP + l * 65536; K = 256; N = 256; k0 = (r >> 2) * 64; n0 = (r & 3) * 64; Nt = 64; }
        else if (ti < 144) { const int l = (ti - 128) >> 2, r = (ti - 128) & 3; src = off_w + l * 16384; dst = WOA + l * 32768; K = 256; N = 64; k0 = r * 64; n0 = 0; Nt = 64; }
        else if (ti < 160) { const int l = (ti - 144) >> 2, r = (ti - 144) & 3; src = aw_w + l * 8192; dst = WOA + l * 32768 + 16384; K = 256; N = 32; k0 = r * 64; n0 = 0; Nt = 32; }
        else if (ti < 168) { const int r = ti - 160; src = w1; dst = WM1; K = 256; N = 128; k0 = (r >> 1) * 64; n0 = (r & 1) * 64; Nt = 64; }
        else if (ti < 170) { const int r = ti - 168; src = w2; dst = WM2; K = 128; N = 64; k0 = r * 64; n0 = 0; Nt = 64; }
        else               { const int r = ti - 170; src = w3; dst = WM3; K = 64; N = 384; k0 = 0; n0 = r * 64; Nt = 64; }
#pragma unroll
        for (int i = 0; i < 4; ++i) {
            const int k = i * 16 + tr;
            if (tc4 < Nt) {
                const float4 vv = *(const float4*)&src[(size_t)(k0 + k) * N + n0 + tc4];
                tile[k][tc4 + 0] = vv.x; tile[k][tc4 + 1] = vv.y;
                tile[k][tc4 + 2] = vv.z; tile[k][tc4 + 3] = vv.w;
            }
        }
        __syncthreads();
#pragma unroll
        for (int i = 0; i < 4; ++i) {
            const int n = i * 16 + tr;
            if (n < Nt) {
                ushort4 o;
                o.x = f2bb(tile[tc4 + 0][n]); o.y = f2bb(tile[tc4 + 1][n]);
                o.z = f2bb(tile[tc4 + 2][n]); o.w = f2bb(tile[tc4 + 3][n]);
                *(ushort4*)&dst[(size_t)(n0 + n) * K + k0 + tc4] = o;
            }
        }
        return;
    }
    if (b < 192) {
        const int z0 = (b - 176) * 2048 + t * 8;
        const int l = z0 >> 13, r = z0 & 8191;
        bf16x8 zz = {0, 0, 0, 0, 0, 0, 0, 0};
        *(bf16x8*)&WOA[(size_t)l * 32768 + 24576 + r] = zz;
        return;
    }
    if (b < 961) {
        const int bb = b - 192;
        if (bb < 768) {
            const bool isq = bb < 384;
            const float* cw = isq ? cqw : cvw;
            const float* lw = isq ? lqw : lvw;
            bf16* W = isq ? WQc : WVc;
            const int idx = (bb % 384) * 256 + t;
            const int n = idx / 384, c = idx % 384;
            float s = 0.f;
            for (int d = 0; d < 256; ++d)
                s = fmaf(cw[d * 384 + c], lw[d * 256 + n], s);
            W[idx] = f2b(s);
        } else {
            const int n = t;
            float sq = lqb[n], sv = lvb[n];
            for (int d = 0; d < 256; ++d) {
                sq = fmaf(cqb[d], lqw[d * 256 + n], sq);
                sv = fmaf(cvb[d], lvw[d * 256 + n], sv);
            }
            BQc[n] = sq; BVc[n] = sv;
        }
        return;
    }
    {
        const int idx = (b - 961) * 256 + t;
        if (idx < 512) {
            const int l = idx >> 7, r = idx & 127;
            OAB[idx] = (r < 64) ? off_b[l * 64 + r] : (r < 96 ? aw_b[l * 32 + r - 64] : 0.f);
        }
    }
}

// fused softmax + bilinear deform sampling; 32 thr/pixel, 8 ch/thread; OA stride 128
__global__ __launch_bounds__(256)
void sample_kernel(const bf16* __restrict__ val, const bf16* __restrict__ oa,
                   bf16* __restrict__ out)
{
    const int tid = threadIdx.x;
    const int pix = blockIdx.x * 8 + (tid >> 5);
    const int thr = tid & 31;
    const int head = thr >> 2;
    const int c0 = thr * 8;
    const float fx = (float)(pix & 127);
    const float fy = (float)(pix >> 7);
    const unsigned short* oap = (const unsigned short*)(oa + (size_t)pix * 128);
    const bf16x8 offs = *(const bf16x8*)&oap[head * 8];
    const ushort4 lg4 = *(const ushort4*)&oap[64 + head * 4];
    const float l0 = us2f(lg4.x), l1 = us2f(lg4.y), l2 = us2f(lg4.z), l3 = us2f(lg4.w);
    const float mx = fmaxf(fmaxf(l0, l1), fmaxf(l2, l3));
    const float e0 = __expf(l0 - mx), e1 = __expf(l1 - mx);
    const float e2 = __expf(l2 - mx), e3 = __expf(l3 - mx);
    const float inv = 1.f / (e0 + e1 + e2 + e3);
    const float aw4[4] = {e0 * inv, e1 * inv, e2 * inv, e3 * inv};

    float acc[8];
#pragma unroll
    for (int c = 0; c < 8; ++c) acc[c] = 0.f;

#pragma unroll
    for (int p = 0; p < 4; ++p) {
        const float x = fx + us2f((unsigned short)offs[p * 2 + 0]);
        const float y = fy + us2f((unsigned short)offs[p * 2 + 1]);
        const float x0f = floorf(x), y0f = floorf(y);
        const float lx = x - x0f, ly = y - y0f;
        const int x0 = (int)x0f, y0 = (int)y0f;
        const float a = aw4[p];
        const float wc[4] = {(1.f - lx) * (1.f - ly) * a, lx * (1.f - ly) * a,
                             (1.f - lx) * ly * a,         lx * ly * a};
        const int xs[4] = {x0, x0 + 1, x0, x0 + 1};
        const int ys[4] = {y0, y0, y0 + 1, y0 + 1};
#pragma unroll
        for (int k = 0; k < 4; ++k) {
            if ((unsigned)ys[k] < 128u && (unsigned)xs[k] < 128u) {
                const bf16x8 v = *(const bf16x8*)&val[(size_t)((ys[k] << 7) + xs[k]) * 256 + c0];
                const float w = wc[k];
#pragma unroll
                for (int c = 0; c < 8; ++c)
                    acc[c] = fmaf(us2f((unsigned short)v[c]), w, acc[c]);
            }
        }
    }
    bf16x8 o;
#pragma unroll
    for (int c = 0; c < 8; ++c) o[c] = (short)f2bb(acc[c]);
    *(bf16x8*)&out[(size_t)pix * 256 + c0] = o;
}

extern "C" void kernel_launch(void* const* d_in, const int* in_sizes, int n_in,
                              void* d_out, int out_size, void* d_ws, size_t ws_size,
                              hipStream_t stream)
{
    const float* query     = (const float*)d_in[0];
    const float* value     = (const float*)d_in[1];
    const float* conv_q_w  = (const float*)d_in[2];
    const float* conv_q_b  = (const float*)d_in[3];
    const float* conv_v_w  = (const float*)d_in[4];
    const float* conv_v_b  = (const float*)d_in[5];
    const float* row_embed = (const float*)d_in[6];
    const float* col_embed = (const float*)d_in[7];
    const float* lin_q_w   = (const float*)d_in[8];
    const float* lin_q_b   = (const float*)d_in[9];
    const float* lin_v_w   = (const float*)d_in[10];
    const float* lin_v_b   = (const float*)d_in[11];
    const float* off_w     = (const float*)d_in[12];
    const float* off_b     = (const float*)d_in[13];
    const float* aw_w      = (const float*)d_in[14];
    const float* aw_b      = (const float*)d_in[15];
    const float* vp_w      = (const float*)d_in[16];
    const float* vp_b      = (const float*)d_in[17];
    const float* op_w      = (const float*)d_in[18];
    const float* op_b      = (const float*)d_in[19];
    const float* out_w1    = (const float*)d_in[20];
    const float* out_b1    = (const float*)d_in[21];
    const float* ln1_g     = (const float*)d_in[22];
    const float* ln1_b     = (const float*)d_in[23];
    const float* out_w2    = (const float*)d_in[24];
    const float* out_b2    = (const float*)d_in[25];
    const float* ln2_g     = (const float*)d_in[26];
    const float* ln2_b     = (const float*)d_in[27];
    const float* out_w3    = (const float*)d_in[28];
    const float* out_b3    = (const float*)d_in[29];

    bf16* w = (bf16*)d_ws;
    auto alloc = [&](size_t n) { bf16* p = w; w += n; return p; };
    bf16* QA  = alloc((size_t)NQ * 256);
    bf16* QB  = alloc((size_t)NQ * 256);
    bf16* QPb = alloc((size_t)NQ * 256);
    bf16* V   = alloc((size_t)NQ * 256);
    bf16* T1  = alloc((size_t)NQ * 256);
    bf16* T2  = alloc((size_t)NQ * 256);
    bf16* VP  = alloc((size_t)3 * NQ * 256);   // vp outputs, layers 0..2
    bf16* OA  = alloc((size_t)NQ * 128);
    bf16* WQc = alloc(256 * 384);
    bf16* WVc = alloc(256 * 384);
    bf16* WVP = alloc(4 * 256 * 256);
    bf16* WOP = alloc(4 * 256 * 256);
    bf16* WOA = alloc(4 * 128 * 256);
    bf16* WM1 = alloc(128 * 256);
    bf16* WM2 = alloc(64 * 128);
    bf16* WM3 = alloc(384 * 64);
    float* fp = (float*)w;
    float* BQc = fp; fp += 256;
    float* BVc = fp; fp += 256;
    float* OAB = fp; fp += 512;

    const dim3 blk(256);

    prep_all<<<963, blk, 0, stream>>>(
        vp_w, op_w, off_w, aw_w, off_b, aw_b, out_w1, out_w2, out_w3,
        WVP, WOP, WOA, WM1, WM2, WM3, OAB,
        conv_q_w, conv_q_b, conv_v_w, conv_v_b,
        lin_q_w, lin_q_b, lin_v_w, lin_v_b,
        WQc, WVc, BQc, BVc);

    gmm_qv<<<dim3(8, 256), blk, 0, stream>>>(
        query, WQc, BQc, QA, QPb, value, WVc, BVc, V, col_embed, row_embed);
    gmm_vpall<<<dim3(14, 256), blk, 0, stream>>>(
        V, WVP, vp_b, VP, QPb, WOA, OAB, OA);

    bf16* cur = QA;
    bf16* nxt = QB;
    for (int i = 0; i < 4; ++i) {
        const bf16* valbuf;
        if (i < 3) {
            valbuf = VP + (size_t)i * NQ * 256;
            if (i > 0)
                gmm_std<1, 8><<<dim3(2, 256), blk, 0, stream>>>(
                    QPb, WOA + (size_t)i * 32768, OAB + i * 128, nullptr,
                    nullptr, nullptr, OA, nullptr, 128);
        } else {
            valbuf = T2;
            gmm_vo3<<<dim3(6, 256), blk, 0, stream>>>(
                cur, WVP + (size_t)3 * 65536, vp_b + 3 * 256, T2,
                QPb, WOA + (size_t)3 * 32768, OAB + 3 * 128, OA);
        }
        sample_kernel<<<2048, blk, 0, stream>>>(valbuf, OA, T1);
        gmm_std<1, 8><<<dim3(4, 256), blk, 0, stream>>>(
            T1, WOP + (size_t)i * 65536, op_b + i * 256, cur,
            col_embed, row_embed, nxt, QPb, 256);
        bf16* tmp = cur; cur = nxt; nxt = tmp;
    }

    // fused MLP tail: mlp1+LN -> mlp2+LN -> out-GEMM (fp32 transposed store)
    mlp_tail<<<256, blk, 0, stream>>>(
        cur, WM1, out_b1, ln1_g, ln1_b,
        WM2, out_b2, ln2_g, ln2_b,
        WM3, out_b3, (float*)d_out);
}